// Round 11
// baseline (101.331 us; speedup 1.0000x reference)
//
#include <hip/hip_runtime.h>

constexpr int Hh = 320, Ww = 320, Cc = 32, Bb = 4, Nn = 20000;
constexpr int HWp = Hh * Ww;

__device__ __forceinline__ float4 shfl_xor4(float4 v, int m) {
  return make_float4(__shfl_xor(v.x, m), __shfl_xor(v.y, m),
                     __shfl_xor(v.z, m), __shfl_xor(v.w, m));
}

// prep: blocks [0,800) fill grids with -1 (int4, full BW); blocks [800,803)
// compute posv[dir][l][c] = pos[l] @ wv_dir.T
__global__ __launch_bounds__(256) void prep_k(
    int* __restrict__ grids, const float* __restrict__ pos,
    const float* __restrict__ in_w1, const float* __restrict__ in_w2,
    float* __restrict__ posv) {
  int bx = blockIdx.x;
  if (bx < 800) {
    int i = bx * 256 + threadIdx.x;  // 800*256 int4 = 2*4*HWp ints exactly
    ((int4*)grids)[i] = make_int4(-1, -1, -1, -1);
    return;
  }
  int t = (bx - 800) * 256 + threadIdx.x;
  if (t >= 2 * 9 * Cc) return;
  int dir = t / (9 * Cc);
  int rem = t - dir * 9 * Cc;
  int l = rem / Cc, ch = rem - l * Cc;
  const float* w = (dir == 0 ? in_w1 : in_w2) + (2 * Cc + ch) * Cc;
  const float* pl = pos + l * Cc;
  float acc = 0.f;
  for (int j = 0; j < Cc; j++) acc += pl[j] * w[j];
  posv[t] = acc;
}

// Fused: blocks [0, PROJ_TOTAL) = K/V projection (register-tiled, 4 pts/thread;
// Q is folded into attn8); blocks [PROJ_TOTAL, +BUILD_BLOCKS) = build_grid.
// K is pre-scaled by 0.25 (= 1/sqrt(HD)) so attn needs no score scaling.
constexpr int PROJ_BLOCKS_PER_SB = 157;              // ceil(20000/128)
constexpr int PROJ_TOTAL = PROJ_BLOCKS_PER_SB * 8;   // 1256
constexpr int BUILD_BLOCKS = 625;                    // 160000/256 exact

__global__ __launch_bounds__(256) void project_build_k(
    const float* __restrict__ li_feats, const float* __restrict__ ra_feats,
    const int* __restrict__ li_coors, const int* __restrict__ ra_coors,
    const float* __restrict__ in_w1, const float* __restrict__ in_w2,
    float* __restrict__ Kp, float* __restrict__ Vp, int* __restrict__ grids) {
  int bx = blockIdx.x;
  if (bx >= PROJ_TOTAL) {
    int idx = (bx - PROJ_TOTAL) * 256 + threadIdx.x;  // [0, 160000) exact
    int src = idx / (Bb * Nn);
    int r = idx - src * (Bb * Nn);
    int b = r / Nn, n = r - b * Nn;
    const int* c = (src == 0 ? li_coors : ra_coors) + ((size_t)b * Nn + n) * 2;
    grids[((size_t)src * Bb + b) * HWp + c[0] * Ww + c[1]] = n;
    return;
  }
  int sb = bx / PROJ_BLOCKS_PER_SB;
  int blk = bx - sb * PROJ_BLOCKS_PER_SB;
  int src = sb >> 2, b = sb & 3;
  // weights transposed, rows padded to 36 floats (9 float4) for bank spread
  __shared__ __align__(16) float wkT[32 * 36];
  __shared__ __align__(16) float wvT[32 * 36];
  const float* wB = src == 0 ? in_w2 : in_w1;  // k/v weights: other direction
  int t = threadIdx.x;
  for (int i = t; i < Cc * Cc; i += 256) {
    int c = i >> 5, j = i & 31;
    wkT[j * 36 + c] = 0.25f * wB[Cc * Cc + i];  // fold 1/sqrt(HD)
    wvT[j * 36 + c] = wB[2 * Cc * Cc + i];
  }
  __syncthreads();
  int quad = t >> 3, c4 = t & 7;
  int n0 = blk * 128 + quad * 4;
  if (n0 + 4 > Nn) n0 = Nn - 4;  // tail clamp: redundant idempotent work
  const float* f = (src == 0 ? li_feats : ra_feats) + ((size_t)b * Nn + n0) * Cc;
  const float4* wk4 = (const float4*)wkT;
  const float4* wv4 = (const float4*)wvT;
  float4 ak[4], av[4];
#pragma unroll
  for (int i = 0; i < 4; i++) {
    ak[i] = make_float4(0.f, 0.f, 0.f, 0.f);
    av[i] = make_float4(0.f, 0.f, 0.f, 0.f);
  }
#pragma unroll
  for (int j4 = 0; j4 < 8; j4++) {
    float fjs[4][4];
#pragma unroll
    for (int i = 0; i < 4; i++) {
      float4 v = ((const float4*)(f + i * Cc))[j4];
      fjs[i][0] = v.x; fjs[i][1] = v.y; fjs[i][2] = v.z; fjs[i][3] = v.w;
    }
#pragma unroll
    for (int u = 0; u < 4; u++) {
      int j = j4 * 4 + u;
      float4 k4 = wk4[j * 9 + c4];
      float4 v4 = wv4[j * 9 + c4];
#pragma unroll
      for (int i = 0; i < 4; i++) {
        float fj = fjs[i][u];
        ak[i].x += fj * k4.x; ak[i].y += fj * k4.y;
        ak[i].z += fj * k4.z; ak[i].w += fj * k4.w;
        av[i].x += fj * v4.x; av[i].y += fj * v4.y;
        av[i].z += fj * v4.z; av[i].w += fj * v4.w;
      }
    }
  }
  int dirkv = 1 - src;
  size_t kvbase = (((size_t)dirkv * Bb + b) * Nn + n0) * Cc + c4 * 4;
#pragma unroll
  for (int i = 0; i < 4; i++) {
    *(float4*)(Kp + kvbase + i * Cc) = ak[i];
    *(float4*)(Vp + kvbase + i * Cc) = av[i];
  }
}

// 8-lane-per-point attention with fused Q projection + output projection.
// Block = 32 points x 8 lanes; lane owns channels [4*c4, 4*c4+4).
// Q-proj: lane loads its coalesced feats float4; 8 xor-rotations against wq
// from LDS produce the lane's 4 qh channels (same pattern as out-proj).
// All 18 K/V gathers issued upfront into registers (independent, one drain).
__global__ __launch_bounds__(256) void attn8_k(
    const float* __restrict__ li_feats, const float* __restrict__ ra_feats,
    const int* __restrict__ li_coors, const int* __restrict__ ra_coors,
    const int* __restrict__ grids,
    const float* __restrict__ Kp, const float* __restrict__ Vp,
    const float* __restrict__ posv, const float* __restrict__ in_w1,
    const float* __restrict__ in_b1, const float* __restrict__ in_b2,
    const float* __restrict__ in_w2, const float* __restrict__ out_w1,
    const float* __restrict__ out_b1, const float* __restrict__ out_w2,
    const float* __restrict__ out_b2, float* __restrict__ out_pts) {
  int db = blockIdx.y;
  int dir = db >> 2, b = db & 3;
  __shared__ __align__(16) float swq[Cc * Cc];
  __shared__ __align__(16) float ow[Cc * Cc];
  __shared__ __align__(16) float pv[9 * Cc];
  __shared__ float sbq[Cc], sbk[Cc], sbv[Cc], sob[Cc];
  const float* wqp = dir == 0 ? in_w1 : in_w2;
  const float* owp = dir == 0 ? out_w1 : out_w2;
  const float* obp = dir == 0 ? out_b1 : out_b2;
  const float* ibp = dir == 0 ? in_b1 : in_b2;
  int t = threadIdx.x;
  for (int i = t; i < Cc * Cc; i += 256) {
    swq[i] = wqp[i];
    ow[i] = owp[i];
  }
  for (int i = t; i < 9 * Cc; i += 256) pv[i] = posv[dir * 9 * Cc + i];
  if (t < Cc) {
    sbq[t] = ibp[t];
    sbk[t] = 0.25f * ibp[Cc + t];  // fold 1/sqrt(HD) (K already pre-scaled)
    sbv[t] = ibp[2 * Cc + t];
    sob[t] = obp[t];
  }
  __syncthreads();
  int pt = t >> 3, c4 = t & 7;
  int n = blockIdx.x * 32 + pt;  // 625*32 == 20000 exact, no tail
  const int2* qcp =
      (const int2*)((dir == 0 ? li_coors : ra_coors) + (size_t)b * Nn * 2);
  int2 yx = qcp[n];
  int y = yx.x, x = yx.y;
  const int* g = grids + ((size_t)(1 - dir) * Bb + b) * HWp;
  const int DY[9] = {0, -1, 1, 0, -1, 1, 0, -1, 1};
  const int DX[9] = {0, 0, 0, 1, 1, 1, -1, -1, -1};
  // ---- issue feats load + all 9 sel loads (independent, 1-deep)
  const float* fb =
      (dir == 0 ? li_feats : ra_feats) + ((size_t)b * Nn + n) * Cc;
  float4 f4 = *(const float4*)(fb + c4 * 4);  // lane's coalesced feats slice
  int sel[9];
#pragma unroll
  for (int l = 0; l < 9; l++) {
    int cy = y + DY[l], cx = x + DX[l];
    sel[l] = ((unsigned)cy < (unsigned)Hh && (unsigned)cx < (unsigned)Ww)
                 ? g[cy * Ww + cx]
                 : -1;
  }
  // ---- issue all K/V gathers into registers (zero when invalid)
  const float* Kpb = Kp + ((size_t)dir * Bb + b) * Nn * Cc;
  const float* Vpb = Vp + ((size_t)dir * Bb + b) * Nn * Cc;
  float4 k4s[9], v4s[9];
#pragma unroll
  for (int l = 0; l < 9; l++) {
    float4 kk = make_float4(0.f, 0.f, 0.f, 0.f);
    float4 vv = make_float4(0.f, 0.f, 0.f, 0.f);
    int se = sel[l];
    if (se >= 0) {
      kk = *(const float4*)(Kpb + (size_t)se * Cc + c4 * 4);
      vv = *(const float4*)(Vpb + (size_t)se * Cc + c4 * 4);
    }
    k4s[l] = kk;
    v4s[l] = vv;
  }
  // ---- Q projection (hides under the gather latency): lane's 4 channels
  const float4* wq4 = (const float4*)swq;
  float4 sbq4 = *(const float4*)(sbq + c4 * 4);
  float q0 = sbq4.x, q1 = sbq4.y, q2 = sbq4.z, q3 = sbq4.w;
#pragma unroll
  for (int mm = 0; mm < 8; mm++) {
    float4 fj = shfl_xor4(f4, mm);  // feats slice of group jb = c4 ^ mm
    int jb = c4 ^ mm;
    float4 w0 = wq4[(c4 * 4 + 0) * 8 + jb];
    float4 w1 = wq4[(c4 * 4 + 1) * 8 + jb];
    float4 w2 = wq4[(c4 * 4 + 2) * 8 + jb];
    float4 w3 = wq4[(c4 * 4 + 3) * 8 + jb];
    q0 += fj.x * w0.x + fj.y * w0.y + fj.z * w0.z + fj.w * w0.w;
    q1 += fj.x * w1.x + fj.y * w1.y + fj.z * w1.z + fj.w * w1.w;
    q2 += fj.x * w2.x + fj.y * w2.y + fj.z * w2.z + fj.w * w2.w;
    q3 += fj.x * w3.x + fj.y * w3.y + fj.z * w3.z + fj.w * w3.w;
  }
  float4 qh4 = make_float4(q0, q1, q2, q3);
  // invalid-slot score: qh . bk_scaled over the lane's head
  float4 bk4 = *(const float4*)(sbk + c4 * 4);
  float pb = qh4.x * bk4.x + qh4.y * bk4.y + qh4.z * bk4.z + qh4.w * bk4.w;
  pb += __shfl_xor(pb, 1);
  pb += __shfl_xor(pb, 2);
  // ---- scores from registers (K pre-scaled; k4s=0 for invalid -> s=pb)
  float s[9];
#pragma unroll
  for (int l = 0; l < 9; l++) {
    float4 k4 = k4s[l];
    float d = qh4.x * k4.x + qh4.y * k4.y + qh4.z * k4.z + qh4.w * k4.w;
    d += __shfl_xor(d, 1);
    d += __shfl_xor(d, 2);  // lane's head dot
    s[l] = pb + d;
  }
  // softmax over 9 slots for the lane's head
  float m = s[0];
#pragma unroll
  for (int l = 1; l < 9; l++) m = fmaxf(m, s[l]);
  float sum = 0.f;
#pragma unroll
  for (int l = 0; l < 9; l++) {
    s[l] = __expf(s[l] - m);
    sum += s[l];
  }
  // ---- PV from registers (posv only for valid slots)
  float4 o4 = make_float4(0.f, 0.f, 0.f, 0.f);
#pragma unroll
  for (int l = 0; l < 9; l++) {
    float wp = (sel[l] >= 0) ? s[l] : 0.f;
    float4 v4 = v4s[l];
    float4 p4 = *(const float4*)(pv + l * Cc + c4 * 4);
    o4.x += wp * (v4.x + p4.x);
    o4.y += wp * (v4.y + p4.y);
    o4.z += wp * (v4.z + p4.z);
    o4.w += wp * (v4.w + p4.w);
  }
  float r = 1.f / sum;
  float4 bv4 = *(const float4*)(sbv + c4 * 4);
  o4 = make_float4(o4.x * r + bv4.x, o4.y * r + bv4.y, o4.z * r + bv4.z,
                   o4.w * r + bv4.w);
  // ---- output projection: lane computes out channels [4*c4, 4*c4+4)
  const float4* ow4 = (const float4*)ow;
  float4 sob4 = *(const float4*)(sob + c4 * 4);
  float acc0 = sob4.x, acc1 = sob4.y, acc2 = sob4.z, acc3 = sob4.w;
#pragma unroll
  for (int mm = 0; mm < 8; mm++) {
    float4 oj = shfl_xor4(o4, mm);  // o slice of group jb = c4 ^ mm
    int jb = c4 ^ mm;
    float4 w0 = ow4[(c4 * 4 + 0) * 8 + jb];
    float4 w1 = ow4[(c4 * 4 + 1) * 8 + jb];
    float4 w2 = ow4[(c4 * 4 + 2) * 8 + jb];
    float4 w3 = ow4[(c4 * 4 + 3) * 8 + jb];
    acc0 += oj.x * w0.x + oj.y * w0.y + oj.z * w0.z + oj.w * w0.w;
    acc1 += oj.x * w1.x + oj.y * w1.y + oj.z * w1.z + oj.w * w1.w;
    acc2 += oj.x * w2.x + oj.y * w2.y + oj.z * w2.z + oj.w * w2.w;
    acc3 += oj.x * w3.x + oj.y * w3.y + oj.z * w3.z + oj.w * w3.w;
  }
  *(float4*)(out_pts + (((size_t)dir * Bb + b) * Nn + n) * Cc + c4 * 4) =
      make_float4(acc0, acc1, acc2, acc3);
}

// Inverted scatter: grid pre-filled, no verify. One thread per canvas pixel;
// channel stores are wave-coalesced full lines.
__global__ __launch_bounds__(256) void scatter_k(
    const int* __restrict__ grids, const float* __restrict__ out_pts,
    float* __restrict__ out) {
  int db = blockIdx.y;
  int dir = db >> 2, b = db & 3;
  int p = blockIdx.x * 256 + threadIdx.x;
  const int* gq = grids + ((size_t)dir * Bb + b) * HWp;
  int se = gq[p];
  float* ob = out + (((size_t)dir * Bb + b) * Cc) * HWp + p;
  if (se < 0) {
#pragma unroll
    for (int c = 0; c < Cc; c++) ob[(size_t)c * HWp] = 0.f;
  } else {
    const float4* sp =
        (const float4*)(out_pts + (((size_t)dir * Bb + b) * Nn + se) * Cc);
#pragma unroll
    for (int c4 = 0; c4 < 8; c4++) {
      float4 v = sp[c4];
      ob[(size_t)(c4 * 4 + 0) * HWp] = v.x;
      ob[(size_t)(c4 * 4 + 1) * HWp] = v.y;
      ob[(size_t)(c4 * 4 + 2) * HWp] = v.z;
      ob[(size_t)(c4 * 4 + 3) * HWp] = v.w;
    }
  }
}

extern "C" void kernel_launch(void* const* d_in, const int* in_sizes, int n_in,
                              void* d_out, int out_size, void* d_ws, size_t ws_size,
                              hipStream_t stream) {
  const float* li_feats = (const float*)d_in[0];
  const int* li_coors = (const int*)d_in[1];
  const float* ra_feats = (const float*)d_in[2];
  const int* ra_coors = (const int*)d_in[3];
  const float* pos = (const float*)d_in[4];
  const float* in_w1 = (const float*)d_in[5];
  const float* in_b1 = (const float*)d_in[6];
  const float* out_w1 = (const float*)d_in[7];
  const float* out_b1 = (const float*)d_in[8];
  const float* in_w2 = (const float*)d_in[9];
  const float* in_b2 = (const float*)d_in[10];
  const float* out_w2 = (const float*)d_in[11];
  const float* out_b2 = (const float*)d_in[12];

  char* ws = (char*)d_ws;
  size_t off = 0;
  int* grids = (int*)(ws + off);
  off += (size_t)2 * Bb * HWp * 4;  // 3,276,800 B
  float* Kp = (float*)(ws + off);
  off += (size_t)2 * Bb * Nn * Cc * 4;  // 20,480,000 B
  float* Vp = (float*)(ws + off);
  off += (size_t)2 * Bb * Nn * Cc * 4;
  float* out_pts = (float*)(ws + off);
  off += (size_t)2 * Bb * Nn * Cc * 4;
  float* posv = (float*)(ws + off);
  off += 2 * 9 * Cc * 4;  // total ~64.7 MB

  prep_k<<<803, 256, 0, stream>>>(grids, pos, in_w1, in_w2, posv);
  project_build_k<<<PROJ_TOTAL + BUILD_BLOCKS, 256, 0, stream>>>(
      li_feats, ra_feats, li_coors, ra_coors, in_w1, in_w2, Kp, Vp, grids);
  dim3 ga(Nn / 32, 2 * Bb);
  attn8_k<<<ga, 256, 0, stream>>>(li_feats, ra_feats, li_coors, ra_coors, grids,
                                  Kp, Vp, posv, in_w1, in_b1, in_b2, in_w2,
                                  out_w1, out_b1, out_w2, out_b2, out_pts);
  dim3 gs(HWp / 256, 2 * Bb);
  scatter_k<<<gs, 256, 0, stream>>>(grids, out_pts, (float*)d_out);
}

// Round 12
// 93.914 us; speedup vs baseline: 1.0790x; 1.0790x over previous
//
#include <hip/hip_runtime.h>

constexpr int Hh = 320, Ww = 320, Cc = 32, Bb = 4, Nn = 20000;
constexpr int HWp = Hh * Ww;

__device__ __forceinline__ float4 shfl_xor4(float4 v, int m) {
  return make_float4(__shfl_xor(v.x, m), __shfl_xor(v.y, m),
                     __shfl_xor(v.z, m), __shfl_xor(v.w, m));
}

// prep: pure grid fill with -1 (int4 stores, full BW).
__global__ __launch_bounds__(256) void prep_k(int* __restrict__ grids) {
  int i = blockIdx.x * 256 + threadIdx.x;  // 800*256 int4 = 2*4*HWp ints exact
  ((int4*)grids)[i] = make_int4(-1, -1, -1, -1);
}

// Fused: blocks [0, PROJ_TOTAL) = Q/K/V projection (register-tiled, 4 pts/thread);
// blocks [PROJ_TOTAL, +BUILD_BLOCKS) = build_grid scatter (grid pre-filled);
// last 3 blocks = posv[dir][l][c] = pos[l] @ wv_dir.T.
// K is pre-scaled by 0.25 (= 1/sqrt(HD)) so attn needs no score scaling.
constexpr int PROJ_BLOCKS_PER_SB = 157;              // ceil(20000/128)
constexpr int PROJ_TOTAL = PROJ_BLOCKS_PER_SB * 8;   // 1256
constexpr int BUILD_BLOCKS = 625;                    // 160000/256 exact

__global__ __launch_bounds__(256) void project_build_k(
    const float* __restrict__ li_feats, const float* __restrict__ ra_feats,
    const int* __restrict__ li_coors, const int* __restrict__ ra_coors,
    const float* __restrict__ pos,
    const float* __restrict__ in_w1, const float* __restrict__ in_b1,
    const float* __restrict__ in_w2, const float* __restrict__ in_b2,
    float* __restrict__ Qh, float* __restrict__ Kp, float* __restrict__ Vp,
    int* __restrict__ grids, float* __restrict__ posv) {
  int bx = blockIdx.x;
  if (bx >= PROJ_TOTAL) {
    if (bx < PROJ_TOTAL + BUILD_BLOCKS) {
      int idx = (bx - PROJ_TOTAL) * 256 + threadIdx.x;  // [0, 160000) exact
      int src = idx / (Bb * Nn);
      int r = idx - src * (Bb * Nn);
      int b = r / Nn, n = r - b * Nn;
      const int* c = (src == 0 ? li_coors : ra_coors) + ((size_t)b * Nn + n) * 2;
      grids[((size_t)src * Bb + b) * HWp + c[0] * Ww + c[1]] = n;
    } else {
      int tt = (bx - PROJ_TOTAL - BUILD_BLOCKS) * 256 + threadIdx.x;
      if (tt < 2 * 9 * Cc) {
        int dir = tt / (9 * Cc);
        int rem = tt - dir * 9 * Cc;
        int l = rem / Cc, ch = rem - l * Cc;
        const float* w = (dir == 0 ? in_w1 : in_w2) + (2 * Cc + ch) * Cc;
        const float* pl = pos + l * Cc;
        float acc = 0.f;
        for (int j = 0; j < Cc; j++) acc += pl[j] * w[j];
        posv[tt] = acc;
      }
    }
    return;
  }
  int sb = bx / PROJ_BLOCKS_PER_SB;
  int blk = bx - sb * PROJ_BLOCKS_PER_SB;
  int src = sb >> 2, b = sb & 3;
  // weights transposed, rows padded to 36 floats (9 float4) for bank spread
  __shared__ __align__(16) float wqT[32 * 36];
  __shared__ __align__(16) float wkT[32 * 36];
  __shared__ __align__(16) float wvT[32 * 36];
  __shared__ float bq[Cc];
  const float* wA = src == 0 ? in_w1 : in_w2;  // q weights: own direction
  const float* bA = src == 0 ? in_b1 : in_b2;
  const float* wB = src == 0 ? in_w2 : in_w1;  // k/v weights: other direction
  int t = threadIdx.x;
  for (int i = t; i < Cc * Cc; i += 256) {
    int c = i >> 5, j = i & 31;
    wqT[j * 36 + c] = wA[i];
    wkT[j * 36 + c] = 0.25f * wB[Cc * Cc + i];  // fold 1/sqrt(HD)
    wvT[j * 36 + c] = wB[2 * Cc * Cc + i];
  }
  if (t < Cc) bq[t] = bA[t];
  __syncthreads();
  int quad = t >> 3, c4 = t & 7;
  int n0 = blk * 128 + quad * 4;
  if (n0 + 4 > Nn) n0 = Nn - 4;  // tail clamp: redundant idempotent work
  const float* f = (src == 0 ? li_feats : ra_feats) + ((size_t)b * Nn + n0) * Cc;
  const float4* wq4 = (const float4*)wqT;
  const float4* wk4 = (const float4*)wkT;
  const float4* wv4 = (const float4*)wvT;
  float4 bq4 = *(const float4*)(bq + c4 * 4);
  float4 aq[4], ak[4], av[4];
#pragma unroll
  for (int i = 0; i < 4; i++) {
    aq[i] = bq4;
    ak[i] = make_float4(0.f, 0.f, 0.f, 0.f);
    av[i] = make_float4(0.f, 0.f, 0.f, 0.f);
  }
#pragma unroll
  for (int j4 = 0; j4 < 8; j4++) {
    float fjs[4][4];
#pragma unroll
    for (int i = 0; i < 4; i++) {
      float4 v = ((const float4*)(f + i * Cc))[j4];
      fjs[i][0] = v.x; fjs[i][1] = v.y; fjs[i][2] = v.z; fjs[i][3] = v.w;
    }
#pragma unroll
    for (int u = 0; u < 4; u++) {
      int j = j4 * 4 + u;
      float4 q4 = wq4[j * 9 + c4];
      float4 k4 = wk4[j * 9 + c4];
      float4 v4 = wv4[j * 9 + c4];
#pragma unroll
      for (int i = 0; i < 4; i++) {
        float fj = fjs[i][u];
        aq[i].x += fj * q4.x; aq[i].y += fj * q4.y;
        aq[i].z += fj * q4.z; aq[i].w += fj * q4.w;
        ak[i].x += fj * k4.x; ak[i].y += fj * k4.y;
        ak[i].z += fj * k4.z; ak[i].w += fj * k4.w;
        av[i].x += fj * v4.x; av[i].y += fj * v4.y;
        av[i].z += fj * v4.z; av[i].w += fj * v4.w;
      }
    }
  }
  int dirkv = 1 - src;
  size_t qbase = (((size_t)src * Bb + b) * Nn + n0) * Cc + c4 * 4;
  size_t kvbase = (((size_t)dirkv * Bb + b) * Nn + n0) * Cc + c4 * 4;
#pragma unroll
  for (int i = 0; i < 4; i++) {
    *(float4*)(Qh + qbase + i * Cc) = aq[i];
    *(float4*)(Kp + kvbase + i * Cc) = ak[i];
    *(float4*)(Vp + kvbase + i * Cc) = av[i];
  }
}

// 8-lane-per-point attention + in-kernel output projection.
// Latency-optimized: Qh load issued first, all 9 sel (1-deep), then ALL 18
// K/V gathers upfront into registers (independent, one drain), then
// dots/softmax/PV entirely from registers. Lane owns channels [4*c4, 4*c4+4).
__global__ __launch_bounds__(256) void attn8_k(
    const int* __restrict__ li_coors, const int* __restrict__ ra_coors,
    const int* __restrict__ grids, const float* __restrict__ Qh,
    const float* __restrict__ Kp, const float* __restrict__ Vp,
    const float* __restrict__ posv, const float* __restrict__ in_b1,
    const float* __restrict__ in_b2, const float* __restrict__ out_w1,
    const float* __restrict__ out_b1, const float* __restrict__ out_w2,
    const float* __restrict__ out_b2, float* __restrict__ out_pts) {
  int db = blockIdx.y;
  int dir = db >> 2, b = db & 3;
  __shared__ __align__(16) float ow[Cc * Cc];
  __shared__ __align__(16) float pv[9 * Cc];
  __shared__ float sbk[Cc], sbv[Cc], sob[Cc];
  const float* owp = dir == 0 ? out_w1 : out_w2;
  const float* obp = dir == 0 ? out_b1 : out_b2;
  const float* ibp = dir == 0 ? in_b1 : in_b2;
  int t = threadIdx.x;
  for (int i = t; i < Cc * Cc; i += 256) ow[i] = owp[i];
  for (int i = t; i < 9 * Cc; i += 256) pv[i] = posv[dir * 9 * Cc + i];
  if (t < Cc) {
    sbk[t] = 0.25f * ibp[Cc + t];  // fold 1/sqrt(HD) (K pre-scaled too)
    sbv[t] = ibp[2 * Cc + t];
    sob[t] = obp[t];
  }
  __syncthreads();
  int pt = t >> 3, c4 = t & 7;
  int n = blockIdx.x * 32 + pt;  // 625*32 == 20000 exact, no tail
  // ---- issue Qh load first (independent; in flight during addr calc)
  float4 qh4 =
      *(const float4*)(Qh + (((size_t)dir * Bb + b) * Nn + n) * Cc + c4 * 4);
  const int2* qcp =
      (const int2*)((dir == 0 ? li_coors : ra_coors) + (size_t)b * Nn * 2);
  int2 yx = qcp[n];
  int y = yx.x, x = yx.y;
  const int* g = grids + ((size_t)(1 - dir) * Bb + b) * HWp;
  const int DY[9] = {0, -1, 1, 0, -1, 1, 0, -1, 1};
  const int DX[9] = {0, 0, 0, 1, 1, 1, -1, -1, -1};
  // ---- phase 1: all 9 sel loads (independent, 1-deep; grid pre-filled)
  int sel[9];
#pragma unroll
  for (int l = 0; l < 9; l++) {
    int cy = y + DY[l], cx = x + DX[l];
    sel[l] = ((unsigned)cy < (unsigned)Hh && (unsigned)cx < (unsigned)Ww)
                 ? g[cy * Ww + cx]
                 : -1;
  }
  // ---- phase 2: issue all K/V gathers into registers (zero when invalid)
  const float* Kpb = Kp + ((size_t)dir * Bb + b) * Nn * Cc;
  const float* Vpb = Vp + ((size_t)dir * Bb + b) * Nn * Cc;
  float4 k4s[9], v4s[9];
#pragma unroll
  for (int l = 0; l < 9; l++) {
    float4 kk = make_float4(0.f, 0.f, 0.f, 0.f);
    float4 vv = make_float4(0.f, 0.f, 0.f, 0.f);
    int se = sel[l];
    if (se >= 0) {
      kk = *(const float4*)(Kpb + (size_t)se * Cc + c4 * 4);
      vv = *(const float4*)(Vpb + (size_t)se * Cc + c4 * 4);
    }
    k4s[l] = kk;
    v4s[l] = vv;
  }
  // invalid-slot score: qh . bk_scaled over the lane's head
  float4 bk4 = *(const float4*)(sbk + c4 * 4);
  float pb = qh4.x * bk4.x + qh4.y * bk4.y + qh4.z * bk4.z + qh4.w * bk4.w;
  pb += __shfl_xor(pb, 1);
  pb += __shfl_xor(pb, 2);
  // ---- phase 3: scores from registers (K pre-scaled; k4s=0 invalid -> s=pb)
  float s[9];
#pragma unroll
  for (int l = 0; l < 9; l++) {
    float4 k4 = k4s[l];
    float d = qh4.x * k4.x + qh4.y * k4.y + qh4.z * k4.z + qh4.w * k4.w;
    d += __shfl_xor(d, 1);
    d += __shfl_xor(d, 2);  // lane's head dot
    s[l] = pb + d;
  }
  // softmax over 9 slots for the lane's head
  float m = s[0];
#pragma unroll
  for (int l = 1; l < 9; l++) m = fmaxf(m, s[l]);
  float sum = 0.f;
#pragma unroll
  for (int l = 0; l < 9; l++) {
    s[l] = __expf(s[l] - m);
    sum += s[l];
  }
  // ---- phase 4: PV from registers (posv only for valid slots)
  float4 o4 = make_float4(0.f, 0.f, 0.f, 0.f);
#pragma unroll
  for (int l = 0; l < 9; l++) {
    float wp = (sel[l] >= 0) ? s[l] : 0.f;
    float4 v4 = v4s[l];
    float4 p4 = *(const float4*)(pv + l * Cc + c4 * 4);
    o4.x += wp * (v4.x + p4.x);
    o4.y += wp * (v4.y + p4.y);
    o4.z += wp * (v4.z + p4.z);
    o4.w += wp * (v4.w + p4.w);
  }
  float r = 1.f / sum;
  float4 bv4 = *(const float4*)(sbv + c4 * 4);
  o4 = make_float4(o4.x * r + bv4.x, o4.y * r + bv4.y, o4.z * r + bv4.z,
                   o4.w * r + bv4.w);
  // ---- output projection: lane computes out channels [4*c4, 4*c4+4)
  const float4* ow4 = (const float4*)ow;
  float4 sob4 = *(const float4*)(sob + c4 * 4);
  float acc0 = sob4.x, acc1 = sob4.y, acc2 = sob4.z, acc3 = sob4.w;
#pragma unroll
  for (int mm = 0; mm < 8; mm++) {
    float4 oj = shfl_xor4(o4, mm);  // o slice of group jb = c4 ^ mm
    int jb = c4 ^ mm;
    float4 w0 = ow4[(c4 * 4 + 0) * 8 + jb];
    float4 w1 = ow4[(c4 * 4 + 1) * 8 + jb];
    float4 w2 = ow4[(c4 * 4 + 2) * 8 + jb];
    float4 w3 = ow4[(c4 * 4 + 3) * 8 + jb];
    acc0 += oj.x * w0.x + oj.y * w0.y + oj.z * w0.z + oj.w * w0.w;
    acc1 += oj.x * w1.x + oj.y * w1.y + oj.z * w1.z + oj.w * w1.w;
    acc2 += oj.x * w2.x + oj.y * w2.y + oj.z * w2.z + oj.w * w2.w;
    acc3 += oj.x * w3.x + oj.y * w3.y + oj.z * w3.z + oj.w * w3.w;
  }
  *(float4*)(out_pts + (((size_t)dir * Bb + b) * Nn + n) * Cc + c4 * 4) =
      make_float4(acc0, acc1, acc2, acc3);
}

// Inverted scatter: grid pre-filled, no verify. One thread per canvas pixel;
// channel stores are wave-coalesced full lines.
__global__ __launch_bounds__(256) void scatter_k(
    const int* __restrict__ grids, const float* __restrict__ out_pts,
    float* __restrict__ out) {
  int db = blockIdx.y;
  int dir = db >> 2, b = db & 3;
  int p = blockIdx.x * 256 + threadIdx.x;
  const int* gq = grids + ((size_t)dir * Bb + b) * HWp;
  int se = gq[p];
  float* ob = out + (((size_t)dir * Bb + b) * Cc) * HWp + p;
  if (se < 0) {
#pragma unroll
    for (int c = 0; c < Cc; c++) ob[(size_t)c * HWp] = 0.f;
  } else {
    const float4* sp =
        (const float4*)(out_pts + (((size_t)dir * Bb + b) * Nn + se) * Cc);
#pragma unroll
    for (int c4 = 0; c4 < 8; c4++) {
      float4 v = sp[c4];
      ob[(size_t)(c4 * 4 + 0) * HWp] = v.x;
      ob[(size_t)(c4 * 4 + 1) * HWp] = v.y;
      ob[(size_t)(c4 * 4 + 2) * HWp] = v.z;
      ob[(size_t)(c4 * 4 + 3) * HWp] = v.w;
    }
  }
}

extern "C" void kernel_launch(void* const* d_in, const int* in_sizes, int n_in,
                              void* d_out, int out_size, void* d_ws, size_t ws_size,
                              hipStream_t stream) {
  const float* li_feats = (const float*)d_in[0];
  const int* li_coors = (const int*)d_in[1];
  const float* ra_feats = (const float*)d_in[2];
  const int* ra_coors = (const int*)d_in[3];
  const float* pos = (const float*)d_in[4];
  const float* in_w1 = (const float*)d_in[5];
  const float* in_b1 = (const float*)d_in[6];
  const float* out_w1 = (const float*)d_in[7];
  const float* out_b1 = (const float*)d_in[8];
  const float* in_w2 = (const float*)d_in[9];
  const float* in_b2 = (const float*)d_in[10];
  const float* out_w2 = (const float*)d_in[11];
  const float* out_b2 = (const float*)d_in[12];

  char* ws = (char*)d_ws;
  size_t off = 0;
  int* grids = (int*)(ws + off);
  off += (size_t)2 * Bb * HWp * 4;  // 3,276,800 B
  float* Qh = (float*)(ws + off);
  off += (size_t)2 * Bb * Nn * Cc * 4;  // 20,480,000 B
  float* Kp = (float*)(ws + off);
  off += (size_t)2 * Bb * Nn * Cc * 4;
  float* Vp = (float*)(ws + off);
  off += (size_t)2 * Bb * Nn * Cc * 4;
  float* out_pts = (float*)(ws + off);
  off += (size_t)2 * Bb * Nn * Cc * 4;
  float* posv = (float*)(ws + off);
  off += 2 * 9 * Cc * 4;  // total ~85.2 MB

  prep_k<<<800, 256, 0, stream>>>(grids);
  project_build_k<<<PROJ_TOTAL + BUILD_BLOCKS + 3, 256, 0, stream>>>(
      li_feats, ra_feats, li_coors, ra_coors, pos, in_w1, in_b1, in_w2, in_b2,
      Qh, Kp, Vp, grids, posv);
  dim3 ga(Nn / 32, 2 * Bb);
  attn8_k<<<ga, 256, 0, stream>>>(li_coors, ra_coors, grids, Qh, Kp, Vp, posv,
                                  in_b1, in_b2, out_w1, out_b1, out_w2, out_b2,
                                  out_pts);
  dim3 gs(HWp / 256, 2 * Bb);
  scatter_k<<<gs, 256, 0, stream>>>(grids, out_pts, (float*)d_out);
}